// Round 12
// baseline (134.070 us; speedup 1.0000x reference)
//
#include <hip/hip_runtime.h>
#include <cstdint>
#include <cstddef>

#define DD    2048
#define NE    8
#define NTOK  4096
#define CAP   512
#define TPB   4                       // tokens per k_finish block
#define NBLK  (NTOK / TPB)            // 1024
#define DISP_ELEMS (NTOK * NE * CAP)  // 16,777,216 floats
#define GATES_OFF  DISP_ELEMS
#define IDX_OFF    (DISP_ELEMS + NTOK * 2)
#define SLICE      (TPB * NE * CAP)   // 16384 floats = 64 KB per finish block

// ---------------------------------------------------------------------------
// k_pre: transpose W[2048][8] -> WT[8][2048] (64 KB, L2-resident afterwards).
// ---------------------------------------------------------------------------
__global__ __launch_bounds__(256) void k_pre(
    const float* __restrict__ W, float* __restrict__ WT)
{
    const int d = blockIdx.x * 256 + threadIdx.x;    // 0..2047
    const float4* W4 = reinterpret_cast<const float4*>(W);
    float4 a = W4[d * 2];        // W[d][0..3]
    float4 b = W4[d * 2 + 1];    // W[d][4..7]
    WT[0 * DD + d] = a.x; WT[1 * DD + d] = a.y;
    WT[2 * DD + d] = a.z; WT[3 * DD + d] = a.w;
    WT[4 * DD + d] = b.x; WT[5 * DD + d] = b.y;
    WT[6 * DD + d] = b.z; WT[7 * DD + d] = b.w;
}

// ---------------------------------------------------------------------------
// k_logits: 4096 blocks x 256, ONE token per block, logits only.
// Half-wave (32 lanes) per expert: thread reads 16 float4 of x (same addrs
// across half-waves -> broadcast) + 16 float4 of WT (coalesced, L2-hot).
// f64 acc, 5-level shfl reduce, thread-0 top-2 + softmax + hist row.
// NO bulk stores in this kernel: avoids the vmcnt store-drain stalling the
// first load consumption (R8 lesson).
// ---------------------------------------------------------------------------
__global__ __launch_bounds__(256) void k_logits(
    const float* __restrict__ x, const float* __restrict__ WT,
    float* __restrict__ out, int2* __restrict__ choices,
    unsigned* __restrict__ hist)   // hist[n*16 + p], p = k*8+e
{
    const int tid = threadIdx.x;
    const int n   = blockIdx.x;
    const int e   = tid >> 5;         // 0..7, half-wave per expert
    const int seg = tid & 31;         // 0..31

    const float4* xr = reinterpret_cast<const float4*>(x) + (size_t)n * (DD / 4);
    const float4* wr = reinterpret_cast<const float4*>(WT) + e * (DD / 4);

    double acc = 0.0;
    #pragma unroll
    for (int j = 0; j < 16; ++j) {
        float4 xv = xr[seg + 32 * j];
        float4 wv = wr[seg + 32 * j];
        acc += (double)xv.x * (double)wv.x;
        acc += (double)xv.y * (double)wv.y;
        acc += (double)xv.z * (double)wv.z;
        acc += (double)xv.w * (double)wv.w;
    }

    #pragma unroll
    for (int off = 1; off < 32; off <<= 1)
        acc += __shfl_xor(acc, off, 64);

    __shared__ double red[NE];
    if ((tid & 31) == 0) red[e] = acc;
    __syncthreads();

    if (tid == 0) {
        float lg[NE];
        #pragma unroll
        for (int q = 0; q < NE; ++q) lg[q] = (float)red[q];

        int e0 = 0;
        #pragma unroll
        for (int q = 1; q < NE; ++q) if (lg[q] > lg[e0]) e0 = q;
        int e1 = -1;
        #pragma unroll
        for (int q = 0; q < NE; ++q) {
            if (q == e0) continue;
            if (e1 < 0 || lg[q] > lg[e1]) e1 = q;
        }

        float p1 = __expf(lg[e1] - lg[e0]);    // lg[e0] >= lg[e1]
        float s  = 1.0f + p1;
        out[GATES_OFF + n * 2 + 0] = 1.0f / s;
        out[GATES_OFF + n * 2 + 1] = p1 / s;
        out[IDX_OFF   + n * 2 + 0] = (float)e0;
        out[IDX_OFF   + n * 2 + 1] = (float)e1;
        int2 c; c.x = e0; c.y = e1;
        choices[n] = c;

        unsigned* h = hist + n * 16;
        #pragma unroll
        for (int p = 0; p < 16; ++p)
            h[p] = (p < 8) ? (unsigned)(p == e0) : (unsigned)((p - 8) == e1);
    }
}

// ---------------------------------------------------------------------------
// k_finish: 1024 blocks x 256 (R7's proven structure). Block bid:
//   A) base[p] = sum over tokens < bid*4 of hist[token][p]. Flat coalesced:
//      thread t sums hist[i] for i ≡ t (mod 256), i < bid*64; i%16 == t%16
//      so each thread touches exactly one pair. LDS 16-way reduce.
//   B) thread 0: in-block ranks for its 4 tokens -> <=8 targets.
//   C) zero its 64 KB dispatcher slice, barrier, patch 1.0f at targets.
// Store-only kernel (plus L2-resident hist reads): BW-bound, no load stalls.
// ---------------------------------------------------------------------------
__global__ __launch_bounds__(256) void k_finish(
    const int2* __restrict__ choices, const unsigned* __restrict__ hist,
    float* __restrict__ out)
{
    __shared__ unsigned partial[256];
    __shared__ unsigned base[16];
    __shared__ int tg[TPB * 2];

    const int tid = threadIdx.x;
    const int bid = blockIdx.x;

    // ---- A: coalesced flat prefix over preceding tokens -----------------
    {
        unsigned s = 0;
        const int lim = bid * (TPB * 16);      // bid*64 u32s
        for (int i = tid; i < lim; i += 256) s += hist[i];
        partial[tid] = s;
    }
    __syncthreads();
    if (tid < 16) {
        unsigned s = 0;
        #pragma unroll
        for (int j = 0; j < 16; ++j) s += partial[tid + 16 * j];
        base[tid] = s;
    }
    __syncthreads();

    // ---- B: targets for this block's 4 tokens ---------------------------
    if (tid == 0) {
        int2 c[TPB];
        #pragma unroll
        for (int t = 0; t < TPB; ++t) c[t] = choices[bid * TPB + t];
        #pragma unroll
        for (int t = 0; t < TPB; ++t) {
            const int e0 = c[t].x;
            unsigned r = 0;
            #pragma unroll
            for (int m = 0; m < TPB; ++m) if (m < t) r += (c[m].x == e0);
            unsigned p0 = base[e0] + r;
            tg[t * 2 + 0] = (p0 < CAP) ? ((t * NE + e0) * CAP + (int)p0) : -1;

            const int e1 = c[t].y;
            r = 0;
            #pragma unroll
            for (int m = 0; m < TPB; ++m) if (m < t) r += (c[m].y == e1);
            unsigned p1 = base[8 + e1] + r;
            tg[t * 2 + 1] = (p1 < CAP) ? ((t * NE + e1) * CAP + (int)p1) : -1;
        }
    }

    // ---- C: zero slice, then patch --------------------------------------
    {
        float4 z = make_float4(0.f, 0.f, 0.f, 0.f);
        float4* dp = reinterpret_cast<float4*>(out) + (size_t)bid * (SLICE / 4);
        #pragma unroll
        for (int i = 0; i < (SLICE / 4) / 256; ++i)            // 16
            dp[i * 256 + tid] = z;
    }
    __syncthreads();
    if (tid < TPB * 2) {
        const int g = tg[tid];
        if (g >= 0) out[(size_t)bid * SLICE + g] = 1.0f;
    }
}

extern "C" void kernel_launch(void* const* d_in, const int* in_sizes, int n_in,
                              void* d_out, int out_size, void* d_ws, size_t ws_size,
                              hipStream_t stream) {
    const float* x = (const float*)d_in[0];
    const float* W = (const float*)d_in[1];
    float* out     = (float*)d_out;

    char* ws = (char*)d_ws;
    float*    WT      = (float*)ws;                       // 64 KB
    int2*     choices = (int2*)(ws + 65536);              // 32 KB
    unsigned* hist    = (unsigned*)(ws + 65536 + 32768);  // 256 KB

    hipLaunchKernelGGL(k_pre,    dim3(8),    dim3(256), 0, stream, W, WT);
    hipLaunchKernelGGL(k_logits, dim3(NTOK), dim3(256), 0, stream,
                       x, WT, out, choices, hist);
    hipLaunchKernelGGL(k_finish, dim3(NBLK), dim3(256), 0, stream,
                       choices, hist, out);
}

// Round 14
// 118.643 us; speedup vs baseline: 1.1300x; 1.1300x over previous
//
#include <hip/hip_runtime.h>
#include <cstdint>
#include <cstddef>

#define DD    2048
#define NE    8
#define NTOK  4096
#define CAP   512
#define TPB   4                       // tokens per logits/finish block
#define NLB   (NTOK / TPB)            // 1024 logits blocks
#define ZBLK  2048                    // zero-role blocks (32 KB each)
#define DISP_ELEMS (NTOK * NE * CAP)  // 16,777,216 floats
#define GATES_OFF  DISP_ELEMS
#define IDX_OFF    (DISP_ELEMS + NTOK * 2)
#define SLICE      (TPB * NE * CAP)   // 16384 floats = 64 KB per 4-token slice

// ---------------------------------------------------------------------------
// k_pre: transpose W[2048][8] -> WT[8][2048] (64 KB, L2-resident afterwards).
// ---------------------------------------------------------------------------
__global__ __launch_bounds__(256) void k_pre(
    const float* __restrict__ W, float* __restrict__ WT)
{
    const int d = blockIdx.x * 256 + threadIdx.x;    // 0..2047
    const float4* W4 = reinterpret_cast<const float4*>(W);
    float4 a = W4[d * 2];        // W[d][0..3]
    float4 b = W4[d * 2 + 1];    // W[d][4..7]
    WT[0 * DD + d] = a.x; WT[1 * DD + d] = a.y;
    WT[2 * DD + d] = a.z; WT[3 * DD + d] = a.w;
    WT[4 * DD + d] = b.x; WT[5 * DD + d] = b.y;
    WT[6 * DD + d] = b.z; WT[7 * DD + d] = b.w;
}

// ---------------------------------------------------------------------------
// k_fused: 3072 blocks x 256, role-split so stores and loads NEVER share a
// block (R8 lesson: shared vmcnt serializes store-drain against load-use).
//   bid < 2048  : pure zero role — stream 32 KB of the dispatcher.
//   bid >= 2048 : pure load role — logits for 4 tokens. Half-wave per
//                 expert (e = tid>>5), seg = tid&31. WT and x reads fully
//                 coalesced float4; x addrs identical across half-waves
//                 (broadcast). f64 acc, 5-level shfl, threads 0-3 finalize.
// Both roles co-resident per CU: store BW overlaps load latency chip-wide.
// ---------------------------------------------------------------------------
__global__ __launch_bounds__(256) void k_fused(
    const float* __restrict__ x, const float* __restrict__ WT,
    float* __restrict__ out, int2* __restrict__ choices,
    unsigned* __restrict__ hist)   // hist[blk4*16 + p], p = k*8+e
{
    const int tid = threadIdx.x;
    const int bid = blockIdx.x;

    __shared__ double redbuf[TPB][NE];
    __shared__ int2   chs[TPB];

    if (bid < ZBLK) {
        // ---- zero role: 32 KB contiguous, nothing else -------------------
        float4 z = make_float4(0.f, 0.f, 0.f, 0.f);
        float4* dp = reinterpret_cast<float4*>(out)
                   + (size_t)bid * (DISP_ELEMS / 4 / ZBLK);    // 2048 f4
        #pragma unroll
        for (int i = 0; i < 8; ++i)
            dp[i * 256 + tid] = z;
        return;
    }

    // ---- logits role ----------------------------------------------------
    const int lb  = bid - ZBLK;       // 0..1023
    const int n0  = lb * TPB;
    const int e   = tid >> 5;         // 0..7
    const int seg = tid & 31;         // 0..31

    const float4* wr = reinterpret_cast<const float4*>(WT) + e * (DD / 4);
    float4 wt[16];
    #pragma unroll
    for (int j = 0; j < 16; ++j)
        wt[j] = wr[seg + 32 * j];

    const float4* x4 = reinterpret_cast<const float4*>(x);
    double acc[TPB] = {0.0, 0.0, 0.0, 0.0};
    #pragma unroll
    for (int j = 0; j < 16; ++j) {
        #pragma unroll
        for (int t = 0; t < TPB; ++t) {
            float4 v = x4[(size_t)(n0 + t) * (DD / 4) + seg + 32 * j];
            acc[t] += (double)v.x * (double)wt[j].x;
            acc[t] += (double)v.y * (double)wt[j].y;
            acc[t] += (double)v.z * (double)wt[j].z;
            acc[t] += (double)v.w * (double)wt[j].w;
        }
    }

    // reduce across the 32 lanes of this half-wave
    #pragma unroll
    for (int off = 1; off < 32; off <<= 1) {
        #pragma unroll
        for (int t = 0; t < TPB; ++t)
            acc[t] += __shfl_xor(acc[t], off, 64);
    }
    if ((tid & 31) == 0) {
        #pragma unroll
        for (int t = 0; t < TPB; ++t)
            redbuf[t][e] = acc[t];
    }
    __syncthreads();

    // per-token finalize: threads 0..3
    if (tid < TPB) {
        const int t = tid;
        const int n = n0 + t;
        float lg[NE];
        #pragma unroll
        for (int q = 0; q < NE; ++q) lg[q] = (float)redbuf[t][q];

        int e0 = 0;
        #pragma unroll
        for (int q = 1; q < NE; ++q) if (lg[q] > lg[e0]) e0 = q;
        int e1 = -1;
        #pragma unroll
        for (int q = 0; q < NE; ++q) {
            if (q == e0) continue;
            if (e1 < 0 || lg[q] > lg[e1]) e1 = q;
        }

        float p1 = __expf(lg[e1] - lg[e0]);    // lg[e0] >= lg[e1]
        float s  = 1.0f + p1;
        out[GATES_OFF + n * 2 + 0] = 1.0f / s;
        out[GATES_OFF + n * 2 + 1] = p1 / s;
        out[IDX_OFF   + n * 2 + 0] = (float)e0;
        out[IDX_OFF   + n * 2 + 1] = (float)e1;
        int2 c; c.x = e0; c.y = e1;
        choices[n] = c;
        chs[t] = c;
    }
    __syncthreads();

    // per-block histogram, layout hist[block][pair]
    if (tid < 16) {
        const int k = tid >> 3, ee = tid & 7;
        unsigned c = 0;
        #pragma unroll
        for (int t = 0; t < TPB; ++t) {
            int v = k ? chs[t].y : chs[t].x;
            c += (v == ee);
        }
        hist[lb * 16 + tid] = c;
    }
}

// ---------------------------------------------------------------------------
// k_finish: 1024 blocks x 256 (R7's proven structure, zero phase removed).
//   A) base[p] = sum over blocks b < bid of hist[b][p] — flat coalesced,
//      thread t sums i ≡ t (mod 256); i%16 == t%16 so one pair per thread.
//   B) thread 0: in-block ranks for its 4 tokens -> <=8 targets.
//   C) patch 1.0f (dispatcher already zeroed by k_fused's zero role).
// ---------------------------------------------------------------------------
__global__ __launch_bounds__(256) void k_finish(
    const int2* __restrict__ choices, const unsigned* __restrict__ hist,
    float* __restrict__ out)
{
    __shared__ unsigned partial[256];
    __shared__ unsigned base[16];
    __shared__ int tg[TPB * 2];

    const int tid = threadIdx.x;
    const int bid = blockIdx.x;

    // ---- A: coalesced flat prefix over preceding 4-token blocks ---------
    {
        unsigned s = 0;
        const int lim = bid * 16;
        for (int i = tid; i < lim; i += 256) s += hist[i];
        partial[tid] = s;
    }
    __syncthreads();
    if (tid < 16) {
        unsigned s = 0;
        #pragma unroll
        for (int j = 0; j < 16; ++j) s += partial[tid + 16 * j];
        base[tid] = s;
    }
    __syncthreads();

    // ---- B: targets for this block's 4 tokens ---------------------------
    if (tid == 0) {
        int2 c[TPB];
        #pragma unroll
        for (int t = 0; t < TPB; ++t) c[t] = choices[bid * TPB + t];
        #pragma unroll
        for (int t = 0; t < TPB; ++t) {
            const int e0 = c[t].x;
            unsigned r = 0;
            #pragma unroll
            for (int m = 0; m < TPB; ++m) if (m < t) r += (c[m].x == e0);
            unsigned p0 = base[e0] + r;
            tg[t * 2 + 0] = (p0 < CAP) ? ((t * NE + e0) * CAP + (int)p0) : -1;

            const int e1 = c[t].y;
            r = 0;
            #pragma unroll
            for (int m = 0; m < TPB; ++m) if (m < t) r += (c[m].y == e1);
            unsigned p1 = base[8 + e1] + r;
            tg[t * 2 + 1] = (p1 < CAP) ? ((t * NE + e1) * CAP + (int)p1) : -1;
        }
    }
    __syncthreads();

    // ---- C: patch only --------------------------------------------------
    if (tid < TPB * 2) {
        const int g = tg[tid];
        if (g >= 0) out[(size_t)bid * SLICE + g] = 1.0f;
    }
}

extern "C" void kernel_launch(void* const* d_in, const int* in_sizes, int n_in,
                              void* d_out, int out_size, void* d_ws, size_t ws_size,
                              hipStream_t stream) {
    const float* x = (const float*)d_in[0];
    const float* W = (const float*)d_in[1];
    float* out     = (float*)d_out;

    char* ws = (char*)d_ws;
    float*    WT      = (float*)ws;                       // 64 KB
    int2*     choices = (int2*)(ws + 65536);              // 32 KB
    unsigned* hist    = (unsigned*)(ws + 65536 + 32768);  // 64 KB

    hipLaunchKernelGGL(k_pre,    dim3(8),          dim3(256), 0, stream, W, WT);
    hipLaunchKernelGGL(k_fused,  dim3(ZBLK + NLB), dim3(256), 0, stream,
                       x, WT, out, choices, hist);
    hipLaunchKernelGGL(k_finish, dim3(NLB),        dim3(256), 0, stream,
                       choices, hist, out);
}